// Round 1
// baseline (970.936 us; speedup 1.0000x reference)
//
#include <hip/hip_runtime.h>

// Problem constants (from reference)
#define F_N 100000
#define C_N 2
#define R_N 500
#define D_N 100            // 25 float4 per feature row
#define NW  3746           // N_WEIGHTS
#define D4  25             // D_N / 4
#define TOTAL (F_N * D4)   // 2,500,000 work items

// BINWIDTHS = {100,200,500,1000,2000,5000}
// BINCUMSTARTS = {0, 2001, 3002, 3403, 3604, 3705}
// Every bw divides 100000 exactly:
//   bin_ix = (c + 100000)/bw + start   (unsigned div)
//   alpha  = ((c + 100000)%bw) / bw

// ---------------------------------------------------------------------------
// Setup kernels: counting sort of features by region id.
// ws layout: [0] int counts[512] | [2048] int cursor[512] | [4096] int4 feat[F_N]
// ---------------------------------------------------------------------------

__global__ void k_init(int* __restrict__ counts) {
    counts[threadIdx.x] = 0;                      // 512 threads, 1 block
}

__global__ __launch_bounds__(256) void k_hist(
    const int* __restrict__ region_ids, int* __restrict__ counts) {
    const int f = blockIdx.x * 256 + threadIdx.x;
    if (f < F_N) atomicAdd(&counts[region_ids[f]], 1);
}

__global__ void k_scan(const int* __restrict__ counts, int* __restrict__ cursor) {
    // single block, 512 threads: exclusive scan of counts[0..499]
    __shared__ int s[512];
    const int t = threadIdx.x;
    const int v = (t < R_N) ? counts[t] : 0;
    s[t] = v;
    __syncthreads();
    for (int off = 1; off < 512; off <<= 1) {
        int x = (t >= off) ? s[t - off] : 0;
        __syncthreads();
        s[t] += x;
        __syncthreads();
    }
    if (t < R_N) cursor[t] = s[t] - v;            // exclusive prefix
}

__global__ __launch_bounds__(256) void k_scatter(
    const int* __restrict__ coords, const int* __restrict__ region_ids,
    int* __restrict__ cursor, int4* __restrict__ feat) {
    const int f = blockIdx.x * 256 + threadIdx.x;
    if (f >= F_N) return;
    const int r = region_ids[f];
    const int pos = atomicAdd(&cursor[r], 1);
    int c0 = coords[2 * f];
    int c1 = coords[2 * f + 1];
    c0 = min(max(c0, -100000), 99999);
    c1 = min(max(c1, -100000), 99999);
    feat[pos] = make_int4(f, r, c0 + 100000, c1 + 100000);
}

// ---------------------------------------------------------------------------
// Main kernel: features arrive region-sorted via feat[]; consecutive blocks
// share a region's 1.5 MB W slab. Bijective XCD-chunk swizzle (m204) keeps
// those consecutive blocks on one XCD so the slab stays hot in its L2.
// ---------------------------------------------------------------------------

__global__ __launch_bounds__(256) void spline_main_kernel(
    const int4*  __restrict__ feat,        // (F,) {f, r, u0, u1} region-sorted
    const float* __restrict__ W,           // (R, NW, D) fp32
    const float* __restrict__ bias,        // (R, D) fp32
    float*       __restrict__ out)         // (F, D) fp32
{
    // bijective chunked XCD swizzle: XCD x processes a contiguous work chunk
    const int nwg = (int)gridDim.x;
    const int q8  = nwg >> 3;
    const int r8  = nwg & 7;
    const int xcd = (int)blockIdx.x & 7;
    const int idx = (int)blockIdx.x >> 3;
    const int wg  = (xcd < r8 ? xcd * (q8 + 1)
                              : r8 * (q8 + 1) + (xcd - r8) * q8) + idx;

    const int gid = wg * 256 + (int)threadIdx.x;
    const int p = gid / D4;                // sorted feature slot
    const int j = gid - p * D4;            // float4 column 0..24
    if (p >= F_N) return;

    const int4 ft = feat[p];
    const int f = ft.x;
    const int r = ft.y;
    const unsigned u0 = (unsigned)ft.z;
    const unsigned u1 = (unsigned)ft.w;

    const float4* __restrict__ Wr =
        (const float4*)(W + (size_t)r * ((size_t)NW * D_N));
    const float4* __restrict__ br =
        (const float4*)(bias + (size_t)r * D_N);

    float4 acc = br[j];

    const unsigned bws[6]    = {100u, 200u, 500u, 1000u, 2000u, 5000u};
    const int      starts[6] = {0, 2001, 3002, 3403, 3604, 3705};

#pragma unroll
    for (int s = 0; s < 6; ++s) {
        const unsigned bw = bws[s];
        const float inv_bw = 1.0f / (float)bw;
        const int st = starts[s];
#pragma unroll
        for (int c = 0; c < 2; ++c) {
            const unsigned u = (c == 0) ? u0 : u1;
            const unsigned q = u / bw;          // constant divisor -> magic mul
            const unsigned rem = u - q * bw;
            const float alpha = (float)rem * inv_bw;
            const float oma = 1.0f - alpha;
            const size_t row = (size_t)(q + (unsigned)st) * D4 + j;
            const float4 w0 = Wr[row];          // W[r, bin,   j*4 ..]
            const float4 w1 = Wr[row + D4];     // W[r, bin+1, j*4 ..]
            acc.x = fmaf(w0.x, oma, acc.x);
            acc.y = fmaf(w0.y, oma, acc.y);
            acc.z = fmaf(w0.z, oma, acc.z);
            acc.w = fmaf(w0.w, oma, acc.w);
            acc.x = fmaf(w1.x, alpha, acc.x);
            acc.y = fmaf(w1.y, alpha, acc.y);
            acc.z = fmaf(w1.z, alpha, acc.z);
            acc.w = fmaf(w1.w, alpha, acc.w);
        }
    }

    ((float4*)out)[(size_t)f * D4 + j] = acc;
}

// ---------------------------------------------------------------------------
// Fallback (previous verified kernel) if workspace is too small.
// ---------------------------------------------------------------------------

__global__ __launch_bounds__(256) void spline_enc_kernel(
    const int*   __restrict__ coords,
    const int*   __restrict__ region_ids,
    const float* __restrict__ W,
    const float* __restrict__ bias,
    float*       __restrict__ out)
{
    const int gid = blockIdx.x * blockDim.x + threadIdx.x;
    const int f = gid / D4;
    const int j = gid % D4;
    if (f >= F_N) return;

    const int r = region_ids[f];
    int c0 = coords[2 * f];
    int c1 = coords[2 * f + 1];
    c0 = min(max(c0, -100000), 99999);
    c1 = min(max(c1, -100000), 99999);
    const unsigned u0 = (unsigned)(c0 + 100000);
    const unsigned u1 = (unsigned)(c1 + 100000);

    const float4* __restrict__ Wr =
        (const float4*)(W + (size_t)r * ((size_t)NW * D_N));
    const float4* __restrict__ br =
        (const float4*)(bias + (size_t)r * D_N);

    float4 acc = br[j];

    const unsigned bws[6]    = {100u, 200u, 500u, 1000u, 2000u, 5000u};
    const int      starts[6] = {0, 2001, 3002, 3403, 3604, 3705};

#pragma unroll
    for (int s = 0; s < 6; ++s) {
        const unsigned bw = bws[s];
        const float inv_bw = 1.0f / (float)bw;
        const int st = starts[s];
#pragma unroll
        for (int c = 0; c < 2; ++c) {
            const unsigned u = (c == 0) ? u0 : u1;
            const unsigned q = u / bw;
            const unsigned rem = u - q * bw;
            const float alpha = (float)rem * inv_bw;
            const float oma = 1.0f - alpha;
            const size_t row = (size_t)(q + (unsigned)st) * D4 + j;
            const float4 w0 = Wr[row];
            const float4 w1 = Wr[row + D4];
            acc.x = fmaf(w0.x, oma, acc.x);
            acc.y = fmaf(w0.y, oma, acc.y);
            acc.z = fmaf(w0.z, oma, acc.z);
            acc.w = fmaf(w0.w, oma, acc.w);
            acc.x = fmaf(w1.x, alpha, acc.x);
            acc.y = fmaf(w1.y, alpha, acc.y);
            acc.z = fmaf(w1.z, alpha, acc.z);
            acc.w = fmaf(w1.w, alpha, acc.w);
        }
    }

    ((float4*)out)[(size_t)f * D4 + j] = acc;
}

// ---------------------------------------------------------------------------

extern "C" void kernel_launch(void* const* d_in, const int* in_sizes, int n_in,
                              void* d_out, int out_size, void* d_ws, size_t ws_size,
                              hipStream_t stream) {
    const int*   coords     = (const int*)d_in[0];
    const int*   region_ids = (const int*)d_in[1];
    const float* W          = (const float*)d_in[2];
    const float* bias       = (const float*)d_in[3];
    float*       out        = (float*)d_out;

    const size_t need = 4096 + sizeof(int4) * (size_t)F_N;
    const int block = 256;
    const int grid_main = (TOTAL + block - 1) / block;

    if (d_ws == nullptr || ws_size < need) {
        // fallback: previous verified single-kernel path
        spline_enc_kernel<<<grid_main, block, 0, stream>>>(
            coords, region_ids, W, bias, out);
        return;
    }

    int*  counts = (int*)d_ws;
    int*  cursor = (int*)((char*)d_ws + 2048);
    int4* feat   = (int4*)((char*)d_ws + 4096);

    const int grid_f = (F_N + block - 1) / block;

    k_init<<<1, 512, 0, stream>>>(counts);
    k_hist<<<grid_f, block, 0, stream>>>(region_ids, counts);
    k_scan<<<1, 512, 0, stream>>>(counts, cursor);
    k_scatter<<<grid_f, block, 0, stream>>>(coords, region_ids, cursor, feat);
    spline_main_kernel<<<grid_main, block, 0, stream>>>(feat, W, bias, out);
}